// Round 5
// baseline (2569.787 us; speedup 1.0000x reference)
//
#include <hip/hip_runtime.h>
#include <cstdint>
#include <cstddef>

#define VV 18000
#define HH 400
#define H3 1200
#define H3P 1280
#define KP 416
#define BB 16
#define TE 256
#define SS 30
#define TDN 8
#define GGN 3
#define SBN 480
#define NROW_ENC 4096
#define VP 18048
#define MP_DEC 512

// encoder recurrence (enc_rnn4): MFMA, hidden-split, relaxed-atomic L3 exchange
#define EBLK 25      // blocks per direction (16 h-columns each)
#define HROW 832     // hbuf row: 416 hi + 416 lo (bf16)

typedef __bf16 bf16;
typedef __attribute__((ext_vector_type(8))) __bf16 bf16x8;
typedef __attribute__((ext_vector_type(4))) float f32x4;

static __device__ __forceinline__ float sigf(float x) {
    return 1.0f / (1.0f + __expf(-x));
}

// ---------------- GEMM: C(MxN, f32, stride N) = A(MxK bf16, row-major) * B(NxK bf16, row-major)^T
__global__ __launch_bounds__(256) void gemm_bt(const bf16* __restrict__ A,
                                               const bf16* __restrict__ B,
                                               float* __restrict__ C,
                                               int M, int N, int K) {
    __shared__ __align__(16) bf16 sA[128 * 32];
    __shared__ __align__(16) bf16 sB[128 * 32];
    const int tid = threadIdx.x;
    const int lane = tid & 63;
    const int wave = tid >> 6;
    const int wm = wave >> 1, wn = wave & 1;
    const int m0 = blockIdx.x * 128, n0 = blockIdx.y * 128;
    f32x4 acc[4][4] = {};
    const int c0 = tid, c1 = tid + 256;
    const int r0 = c0 >> 2, q0 = (c0 & 3) * 8;
    const int r1 = c1 >> 2, q1 = (c1 & 3) * 8;
    const int ar = lane & 15, ak = (lane >> 4) * 8;
    const int nk = K >> 5;
    for (int kt = 0; kt < nk; ++kt) {
        const int kb = kt * 32;
        uint4 a0 = *(const uint4*)(A + (size_t)(m0 + r0) * K + kb + q0);
        uint4 a1 = *(const uint4*)(A + (size_t)(m0 + r1) * K + kb + q1);
        uint4 b0 = *(const uint4*)(B + (size_t)(n0 + r0) * K + kb + q0);
        uint4 b1 = *(const uint4*)(B + (size_t)(n0 + r1) * K + kb + q1);
        __syncthreads();
        *(uint4*)(sA + r0 * 32 + q0) = a0;
        *(uint4*)(sA + r1 * 32 + q1) = a1;
        *(uint4*)(sB + r0 * 32 + q0) = b0;
        *(uint4*)(sB + r1 * 32 + q1) = b1;
        __syncthreads();
        bf16x8 af[4], bg[4];
#pragma unroll
        for (int i = 0; i < 4; ++i)
            af[i] = *(const bf16x8*)(sA + (wm * 64 + i * 16 + ar) * 32 + ak);
#pragma unroll
        for (int j = 0; j < 4; ++j)
            bg[j] = *(const bf16x8*)(sB + (wn * 64 + j * 16 + ar) * 32 + ak);
#pragma unroll
        for (int i = 0; i < 4; ++i)
#pragma unroll
            for (int j = 0; j < 4; ++j)
                acc[i][j] = __builtin_amdgcn_mfma_f32_16x16x32_bf16(af[i], bg[j], acc[i][j], 0, 0, 0);
    }
    const int cr = (lane >> 4) * 4, cc = lane & 15;
#pragma unroll
    for (int i = 0; i < 4; ++i)
#pragma unroll
        for (int j = 0; j < 4; ++j)
#pragma unroll
            for (int q = 0; q < 4; ++q) {
                int row = m0 + wm * 64 + i * 16 + cr + q;
                int col = n0 + wn * 64 + j * 16 + cc;
                C[(size_t)row * N + col] = acc[i][j][q];
            }
}

// ---------------- prep kernels ----------------
__global__ void prep_pad_bf16(const float* __restrict__ src, bf16* __restrict__ dst,
                              int rows_real, int cols_real, int rows_pad, int cols_pad) {
    int idx = blockIdx.x * blockDim.x + threadIdx.x;
    int total = rows_pad * cols_pad;
    if (idx >= total) return;
    int r = idx / cols_pad, c = idx % cols_pad;
    float v = (r < rows_real && c < cols_real) ? src[(size_t)r * cols_real + c] : 0.f;
    dst[idx] = (bf16)v;
}

__global__ void prep_aenc(const int* __restrict__ story, const float* __restrict__ emb,
                          bf16* __restrict__ dst) {
    int idx = blockIdx.x * blockDim.x + threadIdx.x;
    if (idx >= NROW_ENC * KP) return;
    int m = idx / KP, k = idx % KP;
    int t = m >> 4, b = m & 15;
    float v = 0.f;
    if (k < HH) {
        int tok = story[b * TE + t];
        v = emb[(size_t)tok * HH + k];
    }
    dst[idx] = (bf16)v;
}

__global__ void prep_decx(const int* __restrict__ target, const float* __restrict__ emb,
                          const float* __restrict__ slot, float* __restrict__ xf,
                          bf16* __restrict__ xb) {
    int idx = blockIdx.x * blockDim.x + threadIdx.x;
    if (idx >= TDN * SBN * KP) return;
    int k = idx % KP;
    int nn = idx / KP;
    int n = nn % SBN;
    int td = nn / SBN;
    int s = n >> 4, b = n & 15;
    float v = 0.f;
    if (k < HH) {
        if (td == 0) v = slot[s * HH + k];
        else {
            int tok = target[(b * SS + s) * TDN + (td - 1)];
            v = emb[(size_t)tok * HH + k];
        }
        xf[((size_t)td * SBN + n) * HH + k] = v;
    }
    xb[idx] = (bf16)v;
}

__global__ void zero_bf16k(bf16* dst, int total) {
    int idx = blockIdx.x * blockDim.x + threadIdx.x;
    if (idx < total) dst[idx] = (bf16)0.f;
}

// ---------------- encoder recurrence v4: MFMA + relaxed agent atomics (no cache flush) ----------
// grid = 2*EBLK; dir = bid&1, blk = bid>>1. Block owns h-cols [blk*16, blk*16+16).
// Waves 0..2 each hold one gate's 16x416 Whh slice as bf16 B-fragments.
// h exchanged via hbuf with RELAXED agent-scope atomics (sc1 path through L3),
// ordered by vmcnt drain at __syncthreads + flag counter. No wbl2/inv in loop.
__global__ __launch_bounds__(256) void enc_rnn4(
    const float* __restrict__ gi_f, const float* __restrict__ gi_b,
    const float* __restrict__ whh_f, const float* __restrict__ whh_b,
    const float* __restrict__ bih_f, const float* __restrict__ bhh_f,
    const float* __restrict__ bih_b, const float* __restrict__ bhh_b,
    float* __restrict__ hist_f, float* __restrict__ hist_b,
    bf16* __restrict__ hbuf_f, bf16* __restrict__ hbuf_b,
    int* __restrict__ cnt) {
    const int dir = blockIdx.x & 1;
    const int blk = blockIdx.x >> 1;
    const int j0 = blk * 16;
    const float* gi  = dir ? gi_b : gi_f;
    const float* whh = dir ? whh_b : whh_f;
    const float* bih = dir ? bih_b : bih_f;
    const float* bhh = dir ? bhh_b : bhh_f;
    float* hist = dir ? hist_b : hist_f;
    bf16*  hbuf = dir ? hbuf_b : hbuf_f;
    int* mycnt = cnt + dir * TE;

    __shared__ float GHL[3 * 256];   // [gate][batch][col]

    const int tid = threadIdx.x;
    const int wv = tid >> 6, lane = tid & 63;

    // update mapping: thread -> cell (batch=tid>>4, col=tid&15)
    const int ub = tid >> 4, ucol = tid & 15;
    const int uj = j0 + ucol;
    const float bihr = bih[uj], bihz = bih[HH + uj], bihg = bih[2 * HH + uj];
    const float bhhr = bhh[uj], bhhz = bhh[HH + uj], bhhg = bhh[2 * HH + uj];

    // B fragments: wave wv (0..2) owns gate wv; lane&15 = output col, (lane>>4)*8 = k base
    bf16x8 Bf[13];
    if (wv < 3) {
        const int brow = wv * HH + j0 + (lane & 15);
        const int kk0 = (lane >> 4) * 8;
#pragma unroll
        for (int ks = 0; ks < 13; ++ks) {
            bf16x8 v;
#pragma unroll
            for (int e = 0; e < 8; ++e) {
                int k = kk0 + ks * 32 + e;
                v[e] = (k < HH) ? (bf16)whh[(size_t)brow * HH + k] : (bf16)0.f;
            }
            Bf[ks] = v;
        }
    }

    union U16 { unsigned long long q[2]; bf16x8 v; };

    float hp = 0.f;  // this thread's cell of h (fp32, register-resident)

    for (int s = 0; s < TE; ++s) {
        const int tt = dir ? (TE - 1 - s) : s;
        // gi prefetch (independent of the flag)
        const float* gir = gi + ((size_t)tt * BB + ub) * H3P;
        float gi0 = gir[uj];
        float gi1 = gir[HH + uj];
        float gi2 = gir[2 * HH + uj];

        f32x4 acc0 = {}, acc1 = {};
        if (s > 0) {
            if (tid == 0) {
                while (__hip_atomic_load(&mycnt[s - 1], __ATOMIC_RELAXED,
                                         __HIP_MEMORY_SCOPE_AGENT) < EBLK)
                    __builtin_amdgcn_s_sleep(1);
            }
            __syncthreads();
            asm volatile("" ::: "memory");
            if (wv < 3) {
                const int ttp = dir ? (tt + 1) : (tt - 1);
                const unsigned long long* h64 =
                    (const unsigned long long*)(hbuf + ((size_t)ttp * BB + (lane & 15)) * HROW)
                    + (lane >> 4) * 2;
                bf16x8 ah[13], al[13];
#pragma unroll
                for (int ks = 0; ks < 13; ++ks) {
                    U16 uh, ul;
                    uh.q[0] = __hip_atomic_load(h64 + ks * 8,       __ATOMIC_RELAXED, __HIP_MEMORY_SCOPE_AGENT);
                    uh.q[1] = __hip_atomic_load(h64 + ks * 8 + 1,   __ATOMIC_RELAXED, __HIP_MEMORY_SCOPE_AGENT);
                    ul.q[0] = __hip_atomic_load(h64 + 104 + ks * 8,     __ATOMIC_RELAXED, __HIP_MEMORY_SCOPE_AGENT);
                    ul.q[1] = __hip_atomic_load(h64 + 104 + ks * 8 + 1, __ATOMIC_RELAXED, __HIP_MEMORY_SCOPE_AGENT);
                    ah[ks] = uh.v;
                    al[ks] = ul.v;
                }
#pragma unroll
                for (int ks = 0; ks < 13; ++ks) {
                    acc0 = __builtin_amdgcn_mfma_f32_16x16x32_bf16(ah[ks], Bf[ks], acc0, 0, 0, 0);
                    acc1 = __builtin_amdgcn_mfma_f32_16x16x32_bf16(al[ks], Bf[ks], acc1, 0, 0, 0);
                }
            }
        }
        // stage gh into LDS: C layout col=lane&15, batch=(lane>>4)*4+q
        if (wv < 3) {
            f32x4 at = acc0 + acc1;
            const int cb0 = wv * 256 + ((lane >> 4) * 4) * 16 + (lane & 15);
            GHL[cb0]      = at[0];
            GHL[cb0 + 16] = at[1];
            GHL[cb0 + 32] = at[2];
            GHL[cb0 + 48] = at[3];
        }
        __syncthreads();

        // GRU update: one cell per thread
        float ghr = GHL[tid];
        float ghz = GHL[256 + tid];
        float ghg = GHL[512 + tid];
        float r = sigf(gi0 + bihr + ghr + bhhr);
        float z = sigf(gi1 + bihz + ghz + bhhz);
        float g = tanhf(gi2 + bihg + r * (ghg + bhhg));
        float hn = (1.f - z) * g + z * hp;
        hp = hn;
        hist[((size_t)tt * BB + ub) * HH + uj] = hn;
        bf16 hi = (bf16)hn;
        bf16 lo = (bf16)(hn - (float)hi);
        unsigned short hi16 = __builtin_bit_cast(unsigned short, hi);
        unsigned short lo16 = __builtin_bit_cast(unsigned short, lo);
        unsigned short* hw16 = (unsigned short*)(hbuf + ((size_t)tt * BB + ub) * HROW);
        __hip_atomic_store(hw16 + uj,       hi16, __ATOMIC_RELAXED, __HIP_MEMORY_SCOPE_AGENT);
        __hip_atomic_store(hw16 + 416 + uj, lo16, __ATOMIC_RELAXED, __HIP_MEMORY_SCOPE_AGENT);

        asm volatile("" ::: "memory");
        __syncthreads();   // drains vmcnt for all threads before the flag update
        if (tid == 0)
            __hip_atomic_fetch_add(&mycnt[s], 1, __ATOMIC_RELAXED, __HIP_MEMORY_SCOPE_AGENT);
    }
}

__global__ void combine_enc(const float* __restrict__ hf, const float* __restrict__ hb,
                            float* __restrict__ enc_out) {
    int idx = blockIdx.x * blockDim.x + threadIdx.x;
    if (idx >= BB * TE * HH) return;
    int hcol = idx % HH;
    int t = (idx / HH) % TE;
    int b = idx / (HH * TE);
    size_t src = ((size_t)t * BB + b) * HH + hcol;
    enc_out[idx] = hf[src] + hb[src];
}

__global__ void init_hdec(const float* __restrict__ hf, const float* __restrict__ hb,
                          float* __restrict__ hdec) {
    int idx = blockIdx.x * blockDim.x + threadIdx.x;
    if (idx >= SBN * HH) return;
    int hcol = idx % HH;
    int n = idx / HH;
    int b = n & 15;
    hdec[idx] = hf[((size_t)(TE - 1) * BB + b) * HH + hcol] + hb[((size_t)b) * HH + hcol];
}

__global__ void conv_h(const float* __restrict__ h, bf16* __restrict__ hb) {
    int idx = blockIdx.x * blockDim.x + threadIdx.x;
    if (idx >= SBN * HH) return;
    int n = idx / HH, k = idx % HH;
    hb[(size_t)n * KP + k] = (bf16)h[idx];
}

__global__ void gru_dec(const float* __restrict__ gi, const float* __restrict__ gh,
                        const float* __restrict__ bih, const float* __restrict__ bhh,
                        const float* __restrict__ hprev, float* __restrict__ hnew) {
    int idx = blockIdx.x * blockDim.x + threadIdx.x;
    if (idx >= SBN * HH) return;
    int n = idx / HH, j = idx % HH;
    const float* gir = gi + (size_t)n * H3P;
    const float* ghr = gh + (size_t)n * H3P;
    float r = sigf(gir[j] + bih[j] + ghr[j] + bhh[j]);
    float z = sigf(gir[HH + j] + bih[HH + j] + ghr[HH + j] + bhh[HH + j]);
    float g = tanhf(gir[2 * HH + j] + bih[2 * HH + j] + r * (ghr[2 * HH + j] + bhh[2 * HH + j]));
    hnew[idx] = (1.f - z) * g + z * hprev[idx];
}

// scores + softmax + context, one block per decoder row n
__global__ __launch_bounds__(256) void attn(const float* __restrict__ h2,
                                            const float* __restrict__ enc,
                                            float* __restrict__ prob,
                                            float* __restrict__ ctx) {
    int n = blockIdx.x, b = n & 15, tid = threadIdx.x;
    __shared__ __align__(16) float hq[HH];
    __shared__ float sc[TE];
    __shared__ float red[4];
    for (int k = tid; k < HH; k += 256) hq[k] = h2[(size_t)n * HH + k];
    __syncthreads();
    const float4* er = (const float4*)(enc + ((size_t)b * TE + tid) * HH);
    const float4* hq4 = (const float4*)hq;
    float acc = 0.f;
#pragma unroll 4
    for (int k = 0; k < HH / 4; ++k) {
        float4 e = er[k];
        float4 hv = hq4[k];
        acc += e.x * hv.x + e.y * hv.y + e.z * hv.z + e.w * hv.w;
    }
    float m = acc;
    for (int d = 32; d; d >>= 1) m = fmaxf(m, __shfl_xor(m, d));
    if ((tid & 63) == 0) red[tid >> 6] = m;
    __syncthreads();
    m = fmaxf(fmaxf(red[0], red[1]), fmaxf(red[2], red[3]));
    __syncthreads();
    float e = __expf(acc - m);
    float ssum = e;
    for (int d = 32; d; d >>= 1) ssum += __shfl_xor(ssum, d);
    if ((tid & 63) == 0) red[tid >> 6] = ssum;
    __syncthreads();
    ssum = red[0] + red[1] + red[2] + red[3];
    float p = e / ssum;
    sc[tid] = p;
    prob[(size_t)n * TE + tid] = p;
    __syncthreads();
    for (int hcol = tid; hcol < HH; hcol += 256) {
        float a = 0.f;
        for (int t = 0; t < TE; ++t) a += sc[t] * enc[((size_t)b * TE + t) * HH + hcol];
        ctx[(size_t)n * HH + hcol] = a;
    }
}

__global__ __launch_bounds__(64) void swgate(const float* __restrict__ h2,
                                             const float* __restrict__ ctx,
                                             const float* __restrict__ dx,
                                             const float* __restrict__ Wr, const float* __restrict__ br,
                                             const float* __restrict__ Wg, const float* __restrict__ bg,
                                             float* __restrict__ sw, float* __restrict__ outg,
                                             int isfirst) {
    int n = blockIdx.x, lane = threadIdx.x;
    float a = 0.f;
    for (int k = lane; k < H3; k += 64) {
        float v = (k < HH) ? h2[(size_t)n * HH + k]
                : (k < 2 * HH) ? ctx[(size_t)n * HH + (k - HH)]
                : dx[(size_t)n * HH + (k - 2 * HH)];
        a += v * Wr[k];
    }
    for (int d = 32; d; d >>= 1) a += __shfl_xor(a, d);
    if (lane == 0) sw[n] = sigf(a + br[0]);
    if (isfirst) {
        for (int g = 0; g < GGN; ++g) {
            float b2 = 0.f;
            for (int k = lane; k < HH; k += 64) b2 += ctx[(size_t)n * HH + k] * Wg[g * HH + k];
            for (int d = 32; d; d >>= 1) b2 += __shfl_xor(b2, d);
            if (lane == 0) outg[n * GGN + g] = b2 + bg[g];
        }
    }
}

__global__ __launch_bounds__(1024) void smax_final(const float* __restrict__ logits,
                                                   const float* __restrict__ sw,
                                                   float* __restrict__ out, int td) {
    int n = blockIdx.x, tid = threadIdx.x;
    __shared__ float red[16];
    __shared__ float bc[2];
    float v[18];
    float mx = -1e30f;
#pragma unroll
    for (int i = 0; i < 18; ++i) {
        int c = tid + (i << 10);
        v[i] = (c < VV) ? logits[(size_t)n * VP + c] : -1e30f;
        mx = fmaxf(mx, v[i]);
    }
    for (int d = 32; d; d >>= 1) mx = fmaxf(mx, __shfl_xor(mx, d));
    if ((tid & 63) == 0) red[tid >> 6] = mx;
    __syncthreads();
    if (tid == 0) {
        float m2 = red[0];
        for (int w = 1; w < 16; ++w) m2 = fmaxf(m2, red[w]);
        bc[0] = m2;
    }
    __syncthreads();
    mx = bc[0];
    float s = 0.f;
#pragma unroll
    for (int i = 0; i < 18; ++i) {
        int c = tid + (i << 10);
        if (c < VV) { v[i] = __expf(v[i] - mx); s += v[i]; }
    }
    for (int d = 32; d; d >>= 1) s += __shfl_xor(s, d);
    if ((tid & 63) == 0) red[tid >> 6] = s;
    __syncthreads();
    if (tid == 0) {
        float s2 = 0.f;
        for (int w = 0; w < 16; ++w) s2 += red[w];
        bc[1] = s2;
    }
    __syncthreads();
    float scale = sw[n] / bc[1];
    float* orow = out + ((size_t)n * TDN + td) * VV;
#pragma unroll
    for (int i = 0; i < 18; ++i) {
        int c = tid + (i << 10);
        if (c < VV) orow[c] = v[i] * scale;
    }
}

__global__ void scatter_ptr(const int* __restrict__ story, const float* __restrict__ prob,
                            const float* __restrict__ sw, float* __restrict__ out, int td) {
    int n = blockIdx.x, t = threadIdx.x, b = n & 15;
    int tok = story[b * TE + t];
    float val = (1.f - sw[n]) * prob[(size_t)n * TE + t];
    atomicAdd(out + ((size_t)n * TDN + td) * VV + tok, val);
}

static inline int cdiv(long long a, long long b) { return (int)((a + b - 1) / b); }

extern "C" void kernel_launch(void* const* d_in, const int* in_sizes, int n_in,
                              void* d_out, int out_size, void* d_ws, size_t ws_size,
                              hipStream_t stream) {
    const int*   story  = (const int*)d_in[0];
    const int*   target = (const int*)d_in[1];
    const float* emb    = (const float*)d_in[2];
    const float* wih_f  = (const float*)d_in[3];
    const float* whh_f  = (const float*)d_in[4];
    const float* bih_f  = (const float*)d_in[5];
    const float* bhh_f  = (const float*)d_in[6];
    const float* wih_b  = (const float*)d_in[7];
    const float* whh_b  = (const float*)d_in[8];
    const float* bih_b  = (const float*)d_in[9];
    const float* bhh_b  = (const float*)d_in[10];
    const float* dwih   = (const float*)d_in[11];
    const float* dwhh   = (const float*)d_in[12];
    const float* dbih   = (const float*)d_in[13];
    const float* dbhh   = (const float*)d_in[14];
    const float* wr     = (const float*)d_in[15];
    const float* brr    = (const float*)d_in[16];
    const float* wgg    = (const float*)d_in[17];
    const float* bgg    = (const float*)d_in[18];
    const float* slot   = (const float*)d_in[19];
    float* out = (float*)d_out;

    char* wsb = (char*)d_ws;
    size_t off = 0;
    auto alloc = [&](size_t bytes) -> char* {
        char* p = wsb + off;
        off = (off + bytes + 255) & ~(size_t)255;
        return p;
    };
    bf16*  embb  = (bf16*)alloc((size_t)VP * KP * 2);
    bf16*  aenc  = (bf16*)alloc((size_t)NROW_ENC * KP * 2);
    bf16*  wfb   = (bf16*)alloc((size_t)H3P * KP * 2);
    bf16*  wbb   = (bf16*)alloc((size_t)H3P * KP * 2);
    bf16*  dwihb = (bf16*)alloc((size_t)H3P * KP * 2);
    bf16*  dwhhb = (bf16*)alloc((size_t)H3P * KP * 2);
    bf16*  decxb = (bf16*)alloc((size_t)TDN * SBN * KP * 2);
    bf16*  h2b   = (bf16*)alloc((size_t)MP_DEC * KP * 2);
    bf16*  hbuff = (bf16*)alloc((size_t)TE * BB * HROW * 2);
    bf16*  hbufb = (bf16*)alloc((size_t)TE * BB * HROW * 2);
    float* gif   = (float*)alloc((size_t)NROW_ENC * H3P * 4);
    float* gib   = (float*)alloc((size_t)NROW_ENC * H3P * 4);
    float* gidec = (float*)alloc((size_t)TDN * SBN * H3P * 4);
    float* ghdec = (float*)alloc((size_t)MP_DEC * H3P * 4);
    float* histf = (float*)alloc((size_t)TE * BB * HH * 4);
    float* histb = (float*)alloc((size_t)TE * BB * HH * 4);
    float* encout= (float*)alloc((size_t)BB * TE * HH * 4);
    float* decxf = (float*)alloc((size_t)TDN * SBN * HH * 4);
    float* hA    = (float*)alloc((size_t)SBN * HH * 4);
    float* hB    = (float*)alloc((size_t)SBN * HH * 4);
    float* ctx   = (float*)alloc((size_t)SBN * HH * 4);
    float* probw = (float*)alloc((size_t)SBN * TE * 4);
    float* sww   = (float*)alloc((size_t)SBN * 4);
    float* logits= (float*)alloc((size_t)MP_DEC * VP * 4);
    int*   cnt   = (int*)alloc((size_t)2 * TE * 4);
    (void)ws_size; (void)in_sizes; (void)n_in; (void)out_size;

    (void)hipMemsetAsync(cnt, 0, (size_t)2 * TE * 4, stream);

    const int thr = 256;
    prep_pad_bf16<<<cdiv((long long)VP * KP, thr), thr, 0, stream>>>(emb, embb, VV, HH, VP, KP);
    prep_aenc<<<cdiv((long long)NROW_ENC * KP, thr), thr, 0, stream>>>(story, emb, aenc);
    prep_pad_bf16<<<cdiv((long long)H3P * KP, thr), thr, 0, stream>>>(wih_f, wfb, H3, HH, H3P, KP);
    prep_pad_bf16<<<cdiv((long long)H3P * KP, thr), thr, 0, stream>>>(wih_b, wbb, H3, HH, H3P, KP);
    prep_pad_bf16<<<cdiv((long long)H3P * KP, thr), thr, 0, stream>>>(dwih, dwihb, H3, HH, H3P, KP);
    prep_pad_bf16<<<cdiv((long long)H3P * KP, thr), thr, 0, stream>>>(dwhh, dwhhb, H3, HH, H3P, KP);
    prep_decx<<<cdiv((long long)TDN * SBN * KP, thr), thr, 0, stream>>>(target, emb, slot, decxf, decxb);
    zero_bf16k<<<cdiv((long long)MP_DEC * KP, thr), thr, 0, stream>>>(h2b, MP_DEC * KP);

    {
        dim3 g(NROW_ENC / 128, H3P / 128);
        gemm_bt<<<g, 256, 0, stream>>>(aenc, wfb, gif, NROW_ENC, H3P, KP);
        gemm_bt<<<g, 256, 0, stream>>>(aenc, wbb, gib, NROW_ENC, H3P, KP);
    }
    {
        dim3 g((TDN * SBN) / 128, H3P / 128);
        gemm_bt<<<g, 256, 0, stream>>>(decxb, dwihb, gidec, TDN * SBN, H3P, KP);
    }

    enc_rnn4<<<2 * EBLK, 256, 0, stream>>>(gif, gib, whh_f, whh_b,
                                           bih_f, bhh_f, bih_b, bhh_b,
                                           histf, histb, hbuff, hbufb, cnt);

    combine_enc<<<cdiv((long long)BB * TE * HH, thr), thr, 0, stream>>>(histf, histb, encout);
    init_hdec<<<cdiv((long long)SBN * HH, thr), thr, 0, stream>>>(histf, histb, hA);

    float* hc = hA;
    float* hn = hB;
    for (int td = 0; td < TDN; ++td) {
        conv_h<<<cdiv((long long)SBN * HH, thr), thr, 0, stream>>>(hc, h2b);
        {
            dim3 g(MP_DEC / 128, H3P / 128);
            gemm_bt<<<g, 256, 0, stream>>>(h2b, dwhhb, ghdec, MP_DEC, H3P, KP);
        }
        gru_dec<<<cdiv((long long)SBN * HH, thr), thr, 0, stream>>>(
            gidec + (size_t)td * SBN * H3P, ghdec, dbih, dbhh, hc, hn);
        conv_h<<<cdiv((long long)SBN * HH, thr), thr, 0, stream>>>(hn, h2b);
        attn<<<SBN, 256, 0, stream>>>(hn, encout, probw, ctx);
        swgate<<<SBN, 64, 0, stream>>>(hn, ctx, decxf + (size_t)td * SBN * HH,
                                       wr, brr, wgg, bgg, sww,
                                       out + (size_t)SBN * TDN * VV, td == 0 ? 1 : 0);
        {
            dim3 g(MP_DEC / 128, VP / 128);
            gemm_bt<<<g, 256, 0, stream>>>(h2b, embb, logits, MP_DEC, VP, KP);
        }
        smax_final<<<SBN, 1024, 0, stream>>>(logits, sww, out, td);
        scatter_ptr<<<SBN, TE, 0, stream>>>(story, probw, sww, out, td);
        float* tmp = hc; hc = hn; hn = tmp;
    }
}

// Round 6
// 2024.529 us; speedup vs baseline: 1.2693x; 1.2693x over previous
//
#include <hip/hip_runtime.h>
#include <cstdint>
#include <cstddef>

#define VV 18000
#define HH 400
#define H3 1200
#define H3P 1280
#define KP 416
#define BB 16
#define TE 256
#define SS 30
#define TDN 8
#define GGN 3
#define SBN 480
#define NROW_ENC 4096
#define VP 18048
#define MP_DEC 512

// encoder recurrence (enc_rnn5): MFMA, hidden-split, sc0sc1 vector-op L3 exchange
#define EBLK 25      // blocks per direction (16 h-columns each)

typedef __bf16 bf16;
typedef __attribute__((ext_vector_type(8))) __bf16 bf16x8;
typedef __attribute__((ext_vector_type(4))) float f32x4;
typedef __attribute__((ext_vector_type(4))) unsigned int u32x4;

static __device__ __forceinline__ float sigf(float x) {
    return 1.0f / (1.0f + __expf(-x));
}

// ---------------- GEMM: C(MxN, f32, stride N) = A(MxK bf16, row-major) * B(NxK bf16, row-major)^T
__global__ __launch_bounds__(256) void gemm_bt(const bf16* __restrict__ A,
                                               const bf16* __restrict__ B,
                                               float* __restrict__ C,
                                               int M, int N, int K) {
    __shared__ __align__(16) bf16 sA[128 * 32];
    __shared__ __align__(16) bf16 sB[128 * 32];
    const int tid = threadIdx.x;
    const int lane = tid & 63;
    const int wave = tid >> 6;
    const int wm = wave >> 1, wn = wave & 1;
    const int m0 = blockIdx.x * 128, n0 = blockIdx.y * 128;
    f32x4 acc[4][4] = {};
    const int c0 = tid, c1 = tid + 256;
    const int r0 = c0 >> 2, q0 = (c0 & 3) * 8;
    const int r1 = c1 >> 2, q1 = (c1 & 3) * 8;
    const int ar = lane & 15, ak = (lane >> 4) * 8;
    const int nk = K >> 5;
    for (int kt = 0; kt < nk; ++kt) {
        const int kb = kt * 32;
        uint4 a0 = *(const uint4*)(A + (size_t)(m0 + r0) * K + kb + q0);
        uint4 a1 = *(const uint4*)(A + (size_t)(m0 + r1) * K + kb + q1);
        uint4 b0 = *(const uint4*)(B + (size_t)(n0 + r0) * K + kb + q0);
        uint4 b1 = *(const uint4*)(B + (size_t)(n0 + r1) * K + kb + q1);
        __syncthreads();
        *(uint4*)(sA + r0 * 32 + q0) = a0;
        *(uint4*)(sA + r1 * 32 + q1) = a1;
        *(uint4*)(sB + r0 * 32 + q0) = b0;
        *(uint4*)(sB + r1 * 32 + q1) = b1;
        __syncthreads();
        bf16x8 af[4], bg[4];
#pragma unroll
        for (int i = 0; i < 4; ++i)
            af[i] = *(const bf16x8*)(sA + (wm * 64 + i * 16 + ar) * 32 + ak);
#pragma unroll
        for (int j = 0; j < 4; ++j)
            bg[j] = *(const bf16x8*)(sB + (wn * 64 + j * 16 + ar) * 32 + ak);
#pragma unroll
        for (int i = 0; i < 4; ++i)
#pragma unroll
            for (int j = 0; j < 4; ++j)
                acc[i][j] = __builtin_amdgcn_mfma_f32_16x16x32_bf16(af[i], bg[j], acc[i][j], 0, 0, 0);
    }
    const int cr = (lane >> 4) * 4, cc = lane & 15;
#pragma unroll
    for (int i = 0; i < 4; ++i)
#pragma unroll
        for (int j = 0; j < 4; ++j)
#pragma unroll
            for (int q = 0; q < 4; ++q) {
                int row = m0 + wm * 64 + i * 16 + cr + q;
                int col = n0 + wn * 64 + j * 16 + cc;
                C[(size_t)row * N + col] = acc[i][j][q];
            }
}

// ---------------- prep kernels ----------------
__global__ void prep_pad_bf16(const float* __restrict__ src, bf16* __restrict__ dst,
                              int rows_real, int cols_real, int rows_pad, int cols_pad) {
    int idx = blockIdx.x * blockDim.x + threadIdx.x;
    int total = rows_pad * cols_pad;
    if (idx >= total) return;
    int r = idx / cols_pad, c = idx % cols_pad;
    float v = (r < rows_real && c < cols_real) ? src[(size_t)r * cols_real + c] : 0.f;
    dst[idx] = (bf16)v;
}

__global__ void prep_aenc(const int* __restrict__ story, const float* __restrict__ emb,
                          bf16* __restrict__ dst) {
    int idx = blockIdx.x * blockDim.x + threadIdx.x;
    if (idx >= NROW_ENC * KP) return;
    int m = idx / KP, k = idx % KP;
    int t = m >> 4, b = m & 15;
    float v = 0.f;
    if (k < HH) {
        int tok = story[b * TE + t];
        v = emb[(size_t)tok * HH + k];
    }
    dst[idx] = (bf16)v;
}

__global__ void prep_decx(const int* __restrict__ target, const float* __restrict__ emb,
                          const float* __restrict__ slot, float* __restrict__ xf,
                          bf16* __restrict__ xb) {
    int idx = blockIdx.x * blockDim.x + threadIdx.x;
    if (idx >= TDN * SBN * KP) return;
    int k = idx % KP;
    int nn = idx / KP;
    int n = nn % SBN;
    int td = nn / SBN;
    int s = n >> 4, b = n & 15;
    float v = 0.f;
    if (k < HH) {
        if (td == 0) v = slot[s * HH + k];
        else {
            int tok = target[(b * SS + s) * TDN + (td - 1)];
            v = emb[(size_t)tok * HH + k];
        }
        xf[((size_t)td * SBN + n) * HH + k] = v;
    }
    xb[idx] = (bf16)v;
}

__global__ void zero_bf16k(bf16* dst, int total) {
    int idx = blockIdx.x * blockDim.x + threadIdx.x;
    if (idx < total) dst[idx] = (bf16)0.f;
}

// ---------------- encoder recurrence v5: MFMA + sc0sc1 coalesced L3 exchange ----------
// grid = 2*EBLK; dir = bid&1, blk = bid>>1. Block owns h-cols [blk*16, blk*16+16).
// Waves 0..2 each hold one gate's 16x416 Whh slice as bf16 B-fragments.
// h exchanged via hbuf (uint per col: hi bf16 | lo bf16 << 16) using PLAIN
// vector loads/stores with sc0 sc1 (coherent at L3, coalesced, no atomic unit).
// Flag counter remains a single relaxed agent atomic per block per step.
__global__ __launch_bounds__(256) void enc_rnn5(
    const float* __restrict__ gi_f, const float* __restrict__ gi_b,
    const float* __restrict__ whh_f, const float* __restrict__ whh_b,
    const float* __restrict__ bih_f, const float* __restrict__ bhh_f,
    const float* __restrict__ bih_b, const float* __restrict__ bhh_b,
    float* __restrict__ hist_f, float* __restrict__ hist_b,
    unsigned int* __restrict__ hbuf_f, unsigned int* __restrict__ hbuf_b,
    int* __restrict__ cnt) {
    const int dir = blockIdx.x & 1;
    const int blk = blockIdx.x >> 1;
    const int j0 = blk * 16;
    const float* gi  = dir ? gi_b : gi_f;
    const float* whh = dir ? whh_b : whh_f;
    const float* bih = dir ? bih_b : bih_f;
    const float* bhh = dir ? bhh_b : bhh_f;
    float* hist = dir ? hist_b : hist_f;
    unsigned int* hbuf = dir ? hbuf_b : hbuf_f;
    int* mycnt = cnt + dir * TE;

    __shared__ float GHL[3 * 256];   // [gate][batch][col]

    const int tid = threadIdx.x;
    const int wv = tid >> 6, lane = tid & 63;

    // update mapping: thread -> cell (batch=tid>>4, col=tid&15)
    const int ub = tid >> 4, ucol = tid & 15;
    const int uj = j0 + ucol;
    const float bihr = bih[uj], bihz = bih[HH + uj], bihg = bih[2 * HH + uj];
    const float bhhr = bhh[uj], bhhz = bhh[HH + uj], bhhg = bhh[2 * HH + uj];

    // B fragments: wave wv (0..2) owns gate wv; lane&15 = output col, (lane>>4)*8 = k base
    const int kk0 = (lane >> 4) * 8;
    bf16x8 Bf[13];
    if (wv < 3) {
        const int brow = wv * HH + j0 + (lane & 15);
#pragma unroll
        for (int ks = 0; ks < 13; ++ks) {
            bf16x8 v;
#pragma unroll
            for (int e = 0; e < 8; ++e) {
                int k = kk0 + ks * 32 + e;
                v[e] = (k < HH) ? (bf16)whh[(size_t)brow * HH + k] : (bf16)0.f;
            }
            Bf[ks] = v;
        }
    }

    union UV { unsigned int d[4]; bf16x8 v; };

    float hp = 0.f;  // this thread's cell of h (fp32, register-resident)

    for (int s = 0; s < TE; ++s) {
        const int tt = dir ? (TE - 1 - s) : s;
        // gi prefetch (independent of the flag)
        const float* gir = gi + ((size_t)tt * BB + ub) * H3P;
        float gi0 = gir[uj];
        float gi1 = gir[HH + uj];
        float gi2 = gir[2 * HH + uj];

        f32x4 acc0 = {}, acc1 = {};
        if (s > 0) {
            if (tid == 0) {
                while (__hip_atomic_load(&mycnt[s - 1], __ATOMIC_RELAXED,
                                         __HIP_MEMORY_SCOPE_AGENT) < EBLK)
                    __builtin_amdgcn_s_sleep(1);
            }
            __syncthreads();
            if (wv < 3) {
                const int ttp = dir ? (tt + 1) : (tt - 1);
                const unsigned int* hrow =
                    hbuf + ((size_t)ttp * BB + (lane & 15)) * KP + kk0;
                u32x4 u[13][2];
#pragma unroll
                for (int ks = 0; ks < 13; ++ks) {
                    asm volatile("global_load_dwordx4 %0, %1, off sc0 sc1"
                                 : "=v"(u[ks][0]) : "v"(hrow + ks * 32));
                    asm volatile("global_load_dwordx4 %0, %1, off sc0 sc1"
                                 : "=v"(u[ks][1]) : "v"(hrow + ks * 32 + 4));
                }
                asm volatile("s_waitcnt vmcnt(0)" ::: "memory");
                __builtin_amdgcn_sched_barrier(0);
#pragma unroll
                for (int ks = 0; ks < 13; ++ks) {
                    u32x4 a = u[ks][0], b = u[ks][1];
                    UV ah, al;
                    ah.d[0] = (a.x & 0xffffu) | (a.y << 16);
                    ah.d[1] = (a.z & 0xffffu) | (a.w << 16);
                    ah.d[2] = (b.x & 0xffffu) | (b.y << 16);
                    ah.d[3] = (b.z & 0xffffu) | (b.w << 16);
                    al.d[0] = (a.x >> 16) | (a.y & 0xffff0000u);
                    al.d[1] = (a.z >> 16) | (a.w & 0xffff0000u);
                    al.d[2] = (b.x >> 16) | (b.y & 0xffff0000u);
                    al.d[3] = (b.z >> 16) | (b.w & 0xffff0000u);
                    acc0 = __builtin_amdgcn_mfma_f32_16x16x32_bf16(ah.v, Bf[ks], acc0, 0, 0, 0);
                    acc1 = __builtin_amdgcn_mfma_f32_16x16x32_bf16(al.v, Bf[ks], acc1, 0, 0, 0);
                }
            }
        }
        // stage gh into LDS: C layout col=lane&15, batch=(lane>>4)*4+q
        if (wv < 3) {
            f32x4 at = acc0 + acc1;
            const int cb0 = wv * 256 + ((lane >> 4) * 4) * 16 + (lane & 15);
            GHL[cb0]      = at[0];
            GHL[cb0 + 16] = at[1];
            GHL[cb0 + 32] = at[2];
            GHL[cb0 + 48] = at[3];
        }
        __syncthreads();

        // GRU update: one cell per thread
        float ghr = GHL[tid];
        float ghz = GHL[256 + tid];
        float ghg = GHL[512 + tid];
        float r = sigf(gi0 + bihr + ghr + bhhr);
        float z = sigf(gi1 + bihz + ghz + bhhz);
        float g = tanhf(gi2 + bihg + r * (ghg + bhhg));
        float hn = (1.f - z) * g + z * hp;
        hp = hn;
        hist[((size_t)tt * BB + ub) * HH + uj] = hn;
        bf16 hi = (bf16)hn;
        bf16 lo = (bf16)(hn - (float)hi);
        unsigned int pk = (unsigned int)__builtin_bit_cast(unsigned short, hi)
                        | ((unsigned int)__builtin_bit_cast(unsigned short, lo) << 16);
        unsigned int* hw = hbuf + ((size_t)tt * BB + ub) * KP + uj;
        asm volatile("global_store_dword %0, %1, off sc0 sc1" :: "v"(hw), "v"(pk) : "memory");

        asm volatile("s_waitcnt vmcnt(0)" ::: "memory");
        __syncthreads();
        if (tid == 0)
            __hip_atomic_fetch_add(&mycnt[s], 1, __ATOMIC_RELAXED, __HIP_MEMORY_SCOPE_AGENT);
    }
}

__global__ void combine_enc(const float* __restrict__ hf, const float* __restrict__ hb,
                            float* __restrict__ enc_out) {
    int idx = blockIdx.x * blockDim.x + threadIdx.x;
    if (idx >= BB * TE * HH) return;
    int hcol = idx % HH;
    int t = (idx / HH) % TE;
    int b = idx / (HH * TE);
    size_t src = ((size_t)t * BB + b) * HH + hcol;
    enc_out[idx] = hf[src] + hb[src];
}

__global__ void init_hdec(const float* __restrict__ hf, const float* __restrict__ hb,
                          float* __restrict__ hdec) {
    int idx = blockIdx.x * blockDim.x + threadIdx.x;
    if (idx >= SBN * HH) return;
    int hcol = idx % HH;
    int n = idx / HH;
    int b = n & 15;
    hdec[idx] = hf[((size_t)(TE - 1) * BB + b) * HH + hcol] + hb[((size_t)b) * HH + hcol];
}

__global__ void conv_h(const float* __restrict__ h, bf16* __restrict__ hb) {
    int idx = blockIdx.x * blockDim.x + threadIdx.x;
    if (idx >= SBN * HH) return;
    int n = idx / HH, k = idx % HH;
    hb[(size_t)n * KP + k] = (bf16)h[idx];
}

__global__ void gru_dec(const float* __restrict__ gi, const float* __restrict__ gh,
                        const float* __restrict__ bih, const float* __restrict__ bhh,
                        const float* __restrict__ hprev, float* __restrict__ hnew) {
    int idx = blockIdx.x * blockDim.x + threadIdx.x;
    if (idx >= SBN * HH) return;
    int n = idx / HH, j = idx % HH;
    const float* gir = gi + (size_t)n * H3P;
    const float* ghr = gh + (size_t)n * H3P;
    float r = sigf(gir[j] + bih[j] + ghr[j] + bhh[j]);
    float z = sigf(gir[HH + j] + bih[HH + j] + ghr[HH + j] + bhh[HH + j]);
    float g = tanhf(gir[2 * HH + j] + bih[2 * HH + j] + r * (ghr[2 * HH + j] + bhh[2 * HH + j]));
    hnew[idx] = (1.f - z) * g + z * hprev[idx];
}

// scores + softmax + context, one block per decoder row n
__global__ __launch_bounds__(256) void attn(const float* __restrict__ h2,
                                            const float* __restrict__ enc,
                                            float* __restrict__ prob,
                                            float* __restrict__ ctx) {
    int n = blockIdx.x, b = n & 15, tid = threadIdx.x;
    __shared__ __align__(16) float hq[HH];
    __shared__ float sc[TE];
    __shared__ float red[4];
    for (int k = tid; k < HH; k += 256) hq[k] = h2[(size_t)n * HH + k];
    __syncthreads();
    const float4* er = (const float4*)(enc + ((size_t)b * TE + tid) * HH);
    const float4* hq4 = (const float4*)hq;
    float acc = 0.f;
#pragma unroll 4
    for (int k = 0; k < HH / 4; ++k) {
        float4 e = er[k];
        float4 hv = hq4[k];
        acc += e.x * hv.x + e.y * hv.y + e.z * hv.z + e.w * hv.w;
    }
    float m = acc;
    for (int d = 32; d; d >>= 1) m = fmaxf(m, __shfl_xor(m, d));
    if ((tid & 63) == 0) red[tid >> 6] = m;
    __syncthreads();
    m = fmaxf(fmaxf(red[0], red[1]), fmaxf(red[2], red[3]));
    __syncthreads();
    float e = __expf(acc - m);
    float ssum = e;
    for (int d = 32; d; d >>= 1) ssum += __shfl_xor(ssum, d);
    if ((tid & 63) == 0) red[tid >> 6] = ssum;
    __syncthreads();
    ssum = red[0] + red[1] + red[2] + red[3];
    float p = e / ssum;
    sc[tid] = p;
    prob[(size_t)n * TE + tid] = p;
    __syncthreads();
    for (int hcol = tid; hcol < HH; hcol += 256) {
        float a = 0.f;
        for (int t = 0; t < TE; ++t) a += sc[t] * enc[((size_t)b * TE + t) * HH + hcol];
        ctx[(size_t)n * HH + hcol] = a;
    }
}

__global__ __launch_bounds__(64) void swgate(const float* __restrict__ h2,
                                             const float* __restrict__ ctx,
                                             const float* __restrict__ dx,
                                             const float* __restrict__ Wr, const float* __restrict__ br,
                                             const float* __restrict__ Wg, const float* __restrict__ bg,
                                             float* __restrict__ sw, float* __restrict__ outg,
                                             int isfirst) {
    int n = blockIdx.x, lane = threadIdx.x;
    float a = 0.f;
    for (int k = lane; k < H3; k += 64) {
        float v = (k < HH) ? h2[(size_t)n * HH + k]
                : (k < 2 * HH) ? ctx[(size_t)n * HH + (k - HH)]
                : dx[(size_t)n * HH + (k - 2 * HH)];
        a += v * Wr[k];
    }
    for (int d = 32; d; d >>= 1) a += __shfl_xor(a, d);
    if (lane == 0) sw[n] = sigf(a + br[0]);
    if (isfirst) {
        for (int g = 0; g < GGN; ++g) {
            float b2 = 0.f;
            for (int k = lane; k < HH; k += 64) b2 += ctx[(size_t)n * HH + k] * Wg[g * HH + k];
            for (int d = 32; d; d >>= 1) b2 += __shfl_xor(b2, d);
            if (lane == 0) outg[n * GGN + g] = b2 + bg[g];
        }
    }
}

__global__ __launch_bounds__(1024) void smax_final(const float* __restrict__ logits,
                                                   const float* __restrict__ sw,
                                                   float* __restrict__ out, int td) {
    int n = blockIdx.x, tid = threadIdx.x;
    __shared__ float red[16];
    __shared__ float bc[2];
    float v[18];
    float mx = -1e30f;
#pragma unroll
    for (int i = 0; i < 18; ++i) {
        int c = tid + (i << 10);
        v[i] = (c < VV) ? logits[(size_t)n * VP + c] : -1e30f;
        mx = fmaxf(mx, v[i]);
    }
    for (int d = 32; d; d >>= 1) mx = fmaxf(mx, __shfl_xor(mx, d));
    if ((tid & 63) == 0) red[tid >> 6] = mx;
    __syncthreads();
    if (tid == 0) {
        float m2 = red[0];
        for (int w = 1; w < 16; ++w) m2 = fmaxf(m2, red[w]);
        bc[0] = m2;
    }
    __syncthreads();
    mx = bc[0];
    float s = 0.f;
#pragma unroll
    for (int i = 0; i < 18; ++i) {
        int c = tid + (i << 10);
        if (c < VV) { v[i] = __expf(v[i] - mx); s += v[i]; }
    }
    for (int d = 32; d; d >>= 1) s += __shfl_xor(s, d);
    if ((tid & 63) == 0) red[tid >> 6] = s;
    __syncthreads();
    if (tid == 0) {
        float s2 = 0.f;
        for (int w = 0; w < 16; ++w) s2 += red[w];
        bc[1] = s2;
    }
    __syncthreads();
    float scale = sw[n] / bc[1];
    float* orow = out + ((size_t)n * TDN + td) * VV;
#pragma unroll
    for (int i = 0; i < 18; ++i) {
        int c = tid + (i << 10);
        if (c < VV) orow[c] = v[i] * scale;
    }
}

__global__ void scatter_ptr(const int* __restrict__ story, const float* __restrict__ prob,
                            const float* __restrict__ sw, float* __restrict__ out, int td) {
    int n = blockIdx.x, t = threadIdx.x, b = n & 15;
    int tok = story[b * TE + t];
    float val = (1.f - sw[n]) * prob[(size_t)n * TE + t];
    atomicAdd(out + ((size_t)n * TDN + td) * VV + tok, val);
}

static inline int cdiv(long long a, long long b) { return (int)((a + b - 1) / b); }

extern "C" void kernel_launch(void* const* d_in, const int* in_sizes, int n_in,
                              void* d_out, int out_size, void* d_ws, size_t ws_size,
                              hipStream_t stream) {
    const int*   story  = (const int*)d_in[0];
    const int*   target = (const int*)d_in[1];
    const float* emb    = (const float*)d_in[2];
    const float* wih_f  = (const float*)d_in[3];
    const float* whh_f  = (const float*)d_in[4];
    const float* bih_f  = (const float*)d_in[5];
    const float* bhh_f  = (const float*)d_in[6];
    const float* wih_b  = (const float*)d_in[7];
    const float* whh_b  = (const float*)d_in[8];
    const float* bih_b  = (const float*)d_in[9];
    const float* bhh_b  = (const float*)d_in[10];
    const float* dwih   = (const float*)d_in[11];
    const float* dwhh   = (const float*)d_in[12];
    const float* dbih   = (const float*)d_in[13];
    const float* dbhh   = (const float*)d_in[14];
    const float* wr     = (const float*)d_in[15];
    const float* brr    = (const float*)d_in[16];
    const float* wgg    = (const float*)d_in[17];
    const float* bgg    = (const float*)d_in[18];
    const float* slot   = (const float*)d_in[19];
    float* out = (float*)d_out;

    char* wsb = (char*)d_ws;
    size_t off = 0;
    auto alloc = [&](size_t bytes) -> char* {
        char* p = wsb + off;
        off = (off + bytes + 255) & ~(size_t)255;
        return p;
    };
    bf16*  embb  = (bf16*)alloc((size_t)VP * KP * 2);
    bf16*  aenc  = (bf16*)alloc((size_t)NROW_ENC * KP * 2);
    bf16*  wfb   = (bf16*)alloc((size_t)H3P * KP * 2);
    bf16*  wbb   = (bf16*)alloc((size_t)H3P * KP * 2);
    bf16*  dwihb = (bf16*)alloc((size_t)H3P * KP * 2);
    bf16*  dwhhb = (bf16*)alloc((size_t)H3P * KP * 2);
    bf16*  decxb = (bf16*)alloc((size_t)TDN * SBN * KP * 2);
    bf16*  h2b   = (bf16*)alloc((size_t)MP_DEC * KP * 2);
    unsigned int* hbuff = (unsigned int*)alloc((size_t)TE * BB * KP * 4);
    unsigned int* hbufb = (unsigned int*)alloc((size_t)TE * BB * KP * 4);
    float* gif   = (float*)alloc((size_t)NROW_ENC * H3P * 4);
    float* gib   = (float*)alloc((size_t)NROW_ENC * H3P * 4);
    float* gidec = (float*)alloc((size_t)TDN * SBN * H3P * 4);
    float* ghdec = (float*)alloc((size_t)MP_DEC * H3P * 4);
    float* histf = (float*)alloc((size_t)TE * BB * HH * 4);
    float* histb = (float*)alloc((size_t)TE * BB * HH * 4);
    float* encout= (float*)alloc((size_t)BB * TE * HH * 4);
    float* decxf = (float*)alloc((size_t)TDN * SBN * HH * 4);
    float* hA    = (float*)alloc((size_t)SBN * HH * 4);
    float* hB    = (float*)alloc((size_t)SBN * HH * 4);
    float* ctx   = (float*)alloc((size_t)SBN * HH * 4);
    float* probw = (float*)alloc((size_t)SBN * TE * 4);
    float* sww   = (float*)alloc((size_t)SBN * 4);
    float* logits= (float*)alloc((size_t)MP_DEC * VP * 4);
    int*   cnt   = (int*)alloc((size_t)2 * TE * 4);
    (void)ws_size; (void)in_sizes; (void)n_in; (void)out_size;

    (void)hipMemsetAsync(cnt, 0, (size_t)2 * TE * 4, stream);

    const int thr = 256;
    prep_pad_bf16<<<cdiv((long long)VP * KP, thr), thr, 0, stream>>>(emb, embb, VV, HH, VP, KP);
    prep_aenc<<<cdiv((long long)NROW_ENC * KP, thr), thr, 0, stream>>>(story, emb, aenc);
    prep_pad_bf16<<<cdiv((long long)H3P * KP, thr), thr, 0, stream>>>(wih_f, wfb, H3, HH, H3P, KP);
    prep_pad_bf16<<<cdiv((long long)H3P * KP, thr), thr, 0, stream>>>(wih_b, wbb, H3, HH, H3P, KP);
    prep_pad_bf16<<<cdiv((long long)H3P * KP, thr), thr, 0, stream>>>(dwih, dwihb, H3, HH, H3P, KP);
    prep_pad_bf16<<<cdiv((long long)H3P * KP, thr), thr, 0, stream>>>(dwhh, dwhhb, H3, HH, H3P, KP);
    prep_decx<<<cdiv((long long)TDN * SBN * KP, thr), thr, 0, stream>>>(target, emb, slot, decxf, decxb);
    zero_bf16k<<<cdiv((long long)MP_DEC * KP, thr), thr, 0, stream>>>(h2b, MP_DEC * KP);

    {
        dim3 g(NROW_ENC / 128, H3P / 128);
        gemm_bt<<<g, 256, 0, stream>>>(aenc, wfb, gif, NROW_ENC, H3P, KP);
        gemm_bt<<<g, 256, 0, stream>>>(aenc, wbb, gib, NROW_ENC, H3P, KP);
    }
    {
        dim3 g((TDN * SBN) / 128, H3P / 128);
        gemm_bt<<<g, 256, 0, stream>>>(decxb, dwihb, gidec, TDN * SBN, H3P, KP);
    }

    enc_rnn5<<<2 * EBLK, 256, 0, stream>>>(gif, gib, whh_f, whh_b,
                                           bih_f, bhh_f, bih_b, bhh_b,
                                           histf, histb, hbuff, hbufb, cnt);

    combine_enc<<<cdiv((long long)BB * TE * HH, thr), thr, 0, stream>>>(histf, histb, encout);
    init_hdec<<<cdiv((long long)SBN * HH, thr), thr, 0, stream>>>(histf, histb, hA);

    float* hc = hA;
    float* hn = hB;
    for (int td = 0; td < TDN; ++td) {
        conv_h<<<cdiv((long long)SBN * HH, thr), thr, 0, stream>>>(hc, h2b);
        {
            dim3 g(MP_DEC / 128, H3P / 128);
            gemm_bt<<<g, 256, 0, stream>>>(h2b, dwhhb, ghdec, MP_DEC, H3P, KP);
        }
        gru_dec<<<cdiv((long long)SBN * HH, thr), thr, 0, stream>>>(
            gidec + (size_t)td * SBN * H3P, ghdec, dbih, dbhh, hc, hn);
        conv_h<<<cdiv((long long)SBN * HH, thr), thr, 0, stream>>>(hn, h2b);
        attn<<<SBN, 256, 0, stream>>>(hn, encout, probw, ctx);
        swgate<<<SBN, 64, 0, stream>>>(hn, ctx, decxf + (size_t)td * SBN * HH,
                                       wr, brr, wgg, bgg, sww,
                                       out + (size_t)SBN * TDN * VV, td == 0 ? 1 : 0);
        {
            dim3 g(MP_DEC / 128, VP / 128);
            gemm_bt<<<g, 256, 0, stream>>>(h2b, embb, logits, MP_DEC, VP, KP);
        }
        smax_final<<<SBN, 1024, 0, stream>>>(logits, sww, out, td);
        scatter_ptr<<<SBN, TE, 0, stream>>>(story, probw, sww, out, td);
        float* tmp = hc; hc = hn; hn = tmp;
    }
}